// Round 14
// baseline (285.916 us; speedup 1.0000x reference)
//
#include <hip/hip_runtime.h>

// ResRGCN: h=x@W1+b1; 2x {per-(dst,rel) mean aggr -> basis-space GEMM + residual}; out=h@W2+b2
// Layer 3 of the reference is dead (output discarded) and is skipped.
// out_conv = [h | z0..z3] @ [root; B_0..B_3] + bias, z_b = sum_r comp[r,b]*mean_r.
// L2-TILED GATHER (r14): sort key = dst*32 + (src>>15)*8 + rel (4 source chunks
// of 32k rows = 4.2MB ~ one XCD L2). All waves sweep chunk 0->3 in loose lockstep
// -> gathers hit L2 instead of the ~32-MSHR L3 path (the ~82us wall, r5-r13).
// Per-rel mean counts span chunks: lane-parallel diff + shfl_xor tree, flush
// multiplies by readlane'd reciprocal. 2-level LDS radix sort as r13 (4096 bkts).

#define HDIM 64
#define RREL 8
#define NB   4     // bases
#define KC2  320   // 64 (self) + 4*64 (basis)
#define NPB  16    // nodes per workgroup
#define APAD 328   // padded LDS row
#define CSH  15    // source chunk shift (32768 rows/chunk)
#define NSEG 32    // 4 chunks x 8 rels per node

typedef short  short8 __attribute__((ext_vector_type(8)));
typedef __bf16 bf16x8 __attribute__((ext_vector_type(8)));
typedef float  f32x4  __attribute__((ext_vector_type(4)));
typedef unsigned int uint;
typedef unsigned short ushort;

static __device__ __forceinline__ ushort f2bf(float f) {
  uint u = __builtin_bit_cast(uint, f);
  u += 0x7FFFu + ((u >> 16) & 1u);
  return (ushort)(u >> 16);
}
static __device__ __forceinline__ float bf2f(ushort s) {
  uint u = ((uint)s) << 16;
  return __builtin_bit_cast(float, u);
}

// ---- weight prep: wt_lin1[j][k]=lin1_w[k][j]; wt_conv[l][j][k] = cat(root_l, B_0..B_3)^T
__global__ void k_prep_wt(const float* __restrict__ lin1_w, const float* __restrict__ bases,
                          const float* __restrict__ root,
                          ushort* __restrict__ wt_lin1, ushort* __restrict__ wt_conv) {
  int t = blockIdx.x * 256 + threadIdx.x;
  if (t < HDIM * HDIM) {
    int j = t >> 6, k = t & 63;
    wt_lin1[t] = f2bf(lin1_w[k * HDIM + j]);
  }
  if (t < 2 * HDIM * KC2) {
    int l = t / (HDIM * KC2);
    int rem = t - l * (HDIM * KC2);
    int j = rem / KC2;
    int k = rem - j * KC2;
    float v;
    if (k < HDIM) {
      v = root[(l * HDIM + k) * HDIM + j];
    } else {
      int b = (k - HDIM) >> 6;
      int i = (k - HDIM) & 63;
      v = bases[((l * NB + b) * HDIM + i) * HDIM + j];
    }
    wt_conv[t] = f2bf(v);
  }
}

// ---- A) coarse histogram over bucket = key>>10 (key = dst*32+(src>>CSH)*8+et)
__global__ void k_chist(const int* __restrict__ src, const int* __restrict__ dst,
                        const int* __restrict__ et, int E, uint* __restrict__ bcnt) {
  __shared__ uint cnt[4096];
  int t = threadIdx.x;
  for (int i = t; i < 4096; i += 256) cnt[i] = 0;
  __syncthreads();
  int per = (E + gridDim.x - 1) / gridDim.x;
  int e0 = blockIdx.x * per;
  int e1 = e0 + per; if (e1 > E) e1 = E;
  for (int e = e0 + t; e < e1; e += 256) {
    uint key = (uint)dst[e] * NSEG + (((uint)src[e] >> CSH) << 3) + (uint)et[e];
    atomicAdd(&cnt[key >> 10], 1u);
  }
  __syncthreads();
  for (int i = t; i < 4096; i += 256)
    if (cnt[i]) atomicAdd(&bcnt[i], cnt[i]);
}

// ---- B) scan bucket counts (4 per thread, capacity 4096) -> offsets + cursors
__global__ void k_scanB(const uint* __restrict__ bcnt, uint* __restrict__ boff,
                        uint* __restrict__ gcur, uint* __restrict__ off8,
                        int NBK, uint M32, uint E) {
  __shared__ uint s[1024];
  int t = threadIdx.x;
  int k4 = t * 4;
  uint v0 = (k4 < NBK) ? bcnt[k4] : 0u;
  uint v1 = (k4 + 1 < NBK) ? bcnt[k4 + 1] : 0u;
  uint v2 = (k4 + 2 < NBK) ? bcnt[k4 + 2] : 0u;
  uint v3 = (k4 + 3 < NBK) ? bcnt[k4 + 3] : 0u;
  uint tsum = v0 + v1 + v2 + v3;
  s[t] = tsum;
  __syncthreads();
  for (int o = 1; o < 1024; o <<= 1) {
    uint u = (t >= o) ? s[t - o] : 0u;
    __syncthreads();
    s[t] += u;
    __syncthreads();
  }
  uint ex = s[t] - tsum;
  if (k4 < NBK)     { boff[k4] = ex;                   gcur[k4] = ex; }
  if (k4 + 1 < NBK) { boff[k4 + 1] = ex + v0;          gcur[k4 + 1] = ex + v0; }
  if (k4 + 2 < NBK) { boff[k4 + 2] = ex + v0 + v1;     gcur[k4 + 2] = ex + v0 + v1; }
  if (k4 + 3 < NBK) { boff[k4 + 3] = ex + v0 + v1 + v2; gcur[k4 + 3] = ex + v0 + v1 + v2; }
  if (t == 1023) boff[NBK] = s[1023];
  if (t == 0) off8[M32] = E;
}

// ---- C) coarse scatter: LDS count -> one reservation per (WG,bucket) -> runs
__global__ void k_cscat(const int* __restrict__ src, const int* __restrict__ dst,
                        const int* __restrict__ et, int E, uint* __restrict__ gcur,
                        uint* __restrict__ tmp) {
  __shared__ uint cnt[4096];
  __shared__ uint base[4096];
  int t = threadIdx.x;
  int per = (E + gridDim.x - 1) / gridDim.x;
  int e0 = blockIdx.x * per;
  int e1 = e0 + per; if (e1 > E) e1 = E;
  for (int i = t; i < 4096; i += 256) cnt[i] = 0;
  __syncthreads();
  for (int e = e0 + t; e < e1; e += 256) {
    uint key = (uint)dst[e] * NSEG + (((uint)src[e] >> CSH) << 3) + (uint)et[e];
    atomicAdd(&cnt[key >> 10], 1u);
  }
  __syncthreads();
  for (int i = t; i < 4096; i += 256) {
    uint c = cnt[i];
    base[i] = c ? atomicAdd(&gcur[i], c) : 0u;
  }
  __syncthreads();
  for (int i = t; i < 4096; i += 256) cnt[i] = 0;
  __syncthreads();
  for (int e = e0 + t; e < e1; e += 256) {
    uint key = (uint)dst[e] * NSEG + (((uint)src[e] >> CSH) << 3) + (uint)et[e];
    uint b = key >> 10;
    uint pos = base[b] + atomicAdd(&cnt[b], 1u);
    tmp[pos] = (uint)src[e] | ((key & 1023u) << 17);   // src(17b) | finekey(10b)
  }
}

// ---- D) fine sort within bucket; writes off8 directly
__global__ void k_fsort(const uint* __restrict__ boff, const uint* __restrict__ tmp,
                        uint* __restrict__ sorted, uint* __restrict__ off8, uint M32) {
  __shared__ uint c2[1024];
  __shared__ uint ex[1024];
  __shared__ uint s[256];
  int t = threadIdx.x;
  uint b = blockIdx.x;
  uint bo = boff[b], be = boff[b + 1];
  for (int i = t; i < 1024; i += 256) c2[i] = 0;
  __syncthreads();
  for (uint i = bo + t; i < be; i += 256) atomicAdd(&c2[tmp[i] >> 17], 1u);
  __syncthreads();
  int k4 = t * 4;
  uint v0 = c2[k4], v1 = c2[k4 + 1], v2 = c2[k4 + 2], v3 = c2[k4 + 3];
  uint tsum = v0 + v1 + v2 + v3;
  s[t] = tsum;
  __syncthreads();
  for (int o = 1; o < 256; o <<= 1) {
    uint u = (t >= o) ? s[t - o] : 0u;
    __syncthreads();
    s[t] += u;
    __syncthreads();
  }
  uint e0x = s[t] - tsum;
  ex[k4]     = e0x;
  ex[k4 + 1] = e0x + v0;
  ex[k4 + 2] = e0x + v0 + v1;
  ex[k4 + 3] = e0x + v0 + v1 + v2;
  __syncthreads();
  uint gbase = b << 10;
  #pragma unroll
  for (int u = 0; u < 4; ++u) {
    uint g = gbase + (uint)(k4 + u);
    if (g < M32) off8[g] = bo + ex[k4 + u];
  }
  for (int i = t; i < 1024; i += 256) c2[i] = 0;   // reuse as cursors
  __syncthreads();
  for (uint i = bo + t; i < be; i += 256) {
    uint w = tmp[i];
    uint fk = w >> 17;
    uint pos = bo + ex[fk] + atomicAdd(&c2[fk], 1u);
    sorted[pos] = w & 0x1FFFFu;
  }
}

// ---- lin1: hb = bf16(x @ W1 + b1) (MFMA over K=64), float4 input loads
__global__ void k_lin1(const float* __restrict__ x, const ushort* __restrict__ wt,
                       const float* __restrict__ bias, ushort* __restrict__ hb, int N) {
  __shared__ ushort A[NPB][72];
  int nodebase = blockIdx.x * NPB;
  {
    int t = threadIdx.x;
    int nl = t >> 4, c = (t & 15) * 4;
    int n = nodebase + nl;
    ushort4 o = {0, 0, 0, 0};
    if (n < N) {
      f32x4 v = *(const f32x4*)&x[(size_t)n * HDIM + c];
      o.x = f2bf(v[0]); o.y = f2bf(v[1]); o.z = f2bf(v[2]); o.w = f2bf(v[3]);
    }
    *(ushort4*)&A[nl][c] = o;
  }
  __syncthreads();
  int lane = threadIdx.x & 63, wid = threadIdx.x >> 6;
  int m16 = lane & 15, khi = lane >> 4;
  int colbase = wid * 16;
  f32x4 acc = {0.f, 0.f, 0.f, 0.f};
  #pragma unroll
  for (int kk = 0; kk < HDIM; kk += 32) {
    int k0 = kk + khi * 8;
    short8 av = *(const short8*)&A[m16][k0];
    short8 bv = *(const short8*)&wt[(colbase + m16) * HDIM + k0];
    acc = __builtin_amdgcn_mfma_f32_16x16x32_bf16(
        __builtin_bit_cast(bf16x8, av), __builtin_bit_cast(bf16x8, bv), acc, 0, 0, 0);
  }
  int j = colbase + m16;
  float bj = bias[j];
  #pragma unroll
  for (int r = 0; r < 4; ++r) {
    int nl = khi * 4 + r;
    int n = nodebase + nl;
    if (n < N) hb[(size_t)n * HDIM + j] = f2bf(acc[r] + bj);
  }
}

// ---- fused RGCN layer: chunk-16 gather walk over 32 (chunk,rel) segments/node,
//      z-basis accumulation in VGPRs; last!=0 fuses lin2 and skips hb_out.
__global__ void __launch_bounds__(256, 6)
k_conv(const uint* __restrict__ off8, const uint* __restrict__ sorted,
       const ushort* __restrict__ hb_in, const float* __restrict__ compL,
       const ushort* __restrict__ wt, const float* __restrict__ bias,
       ushort* __restrict__ hb_out, int N, int last,
       const float* __restrict__ w2, const float* __restrict__ b2,
       float* __restrict__ out) {
  __shared__ ushort A[NPB][APAD];     // 10.5 KB
  __shared__ float  cmp[RREL * NB];
  __shared__ float  accO[NPB][2];
  int nb0 = blockIdx.x * NPB;
  int lane = threadIdx.x & 63, wid = threadIdx.x >> 6;

  if (threadIdx.x < RREL * NB) cmp[threadIdx.x] = compL[threadIdx.x];
  if (threadIdx.x < NPB * 2) accO[threadIdx.x >> 1][threadIdx.x & 1] = 0.f;
  {
    int t = threadIdx.x;
    int nl = t >> 4, c = (t & 15) * 4;
    int n = nb0 + nl;
    uint2 v = {0u, 0u};
    if (n < N) v = *(const uint2*)&hb_in[(size_t)n * HDIM + c];
    *(uint2*)&A[nl][c] = v;
  }
  __syncthreads();

  const ushort* hlane = hb_in + lane;
  for (int q = 0; q < 4; ++q) {
    int nl = wid * 4 + q;
    int n = nb0 + nl;
    if (n < N) {
      // 33 boundaries (4 chunks x 8 rels) in lanes 0..32; others UINT_MAX
      uint bv = 0xFFFFFFFFu;
      if (lane < NSEG + 1) bv = off8[(uint)n * NSEG + (uint)lane];
      // per-rel TOTAL counts across chunks: diff + xor-tree (lane r<8 -> cnt_r)
      uint nxt = (uint)__shfl((int)bv, lane + 1);
      uint d = (lane < NSEG) ? (nxt - bv) : 0u;
      d += (uint)__shfl_xor((int)d, 8);
      d += (uint)__shfl_xor((int)d, 16);
      float rcpv = __builtin_amdgcn_rcpf(fmaxf((float)d, 1.0f));
      int rcpi = __builtin_bit_cast(int, rcpv);

      uint s0 = (uint)__builtin_amdgcn_readlane((int)bv, 0);
      uint s1 = (uint)__builtin_amdgcn_readlane((int)bv, NSEG);
      float run = 0.f, z0 = 0.f, z1 = 0.f, z2 = 0.f, z3 = 0.f;
      int ri = 0;
      uint nextb = (uint)__builtin_amdgcn_readlane((int)bv, 1);
      for (uint base = s0; base < s1; base += 16u) {
        const uint* sp = sorted + base;
        uint4 w0 = *(const uint4*)(sp);
        uint4 w1 = *(const uint4*)(sp + 4);
        uint4 w2v = *(const uint4*)(sp + 8);
        uint4 w3 = *(const uint4*)(sp + 12);
        uint idx[16] = {w0.x, w0.y, w0.z, w0.w, w1.x, w1.y, w1.z, w1.w,
                        w2v.x, w2v.y, w2v.z, w2v.w, w3.x, w3.y, w3.z, w3.w};
        float g[16];
        #pragma unroll
        for (int j = 0; j < 16; ++j) {
          uint ij = (uint)__builtin_amdgcn_readfirstlane((int)idx[j]) & 0x1FFFFu;
          g[j] = bf2f(hlane[(size_t)ij << 6]);    // SGPR base + lane*2 voffset
        }
        uint m = s1 - base;                        // scalar
        if (m > 16u) m = 16u;
        #pragma unroll
        for (int j = 0; j < 16; ++j) {
          if ((uint)j < m) {                       // scalar guard
            uint pos = base + (uint)j;
            while (pos >= nextb) {                 // scalar flush walk -> z accum
              int rel = ri & 7;
              float rc = __builtin_bit_cast(float, __builtin_amdgcn_readlane(rcpi, rel));
              float mp = run * rc;
              f32x4 c4 = *(const f32x4*)&cmp[rel * NB];
              z0 += c4[0] * mp; z1 += c4[1] * mp;
              z2 += c4[2] * mp; z3 += c4[3] * mp;
              run = 0.f;
              ++ri;
              nextb = (uint)__builtin_amdgcn_readlane((int)bv, ri + 1);
            }
            run += g[j];
          }
        }
      }
      while (ri < NSEG) {                          // trailing flushes
        int rel = ri & 7;
        float rc = __builtin_bit_cast(float, __builtin_amdgcn_readlane(rcpi, rel));
        float mp = run * rc;
        f32x4 c4 = *(const f32x4*)&cmp[rel * NB];
        z0 += c4[0] * mp; z1 += c4[1] * mp;
        z2 += c4[2] * mp; z3 += c4[3] * mp;
        run = 0.f;
        ++ri;
        if (ri < NSEG) nextb = (uint)__builtin_amdgcn_readlane((int)bv, ri + 1);
      }
      A[nl][HDIM + 0 * HDIM + lane] = f2bf(z0);
      A[nl][HDIM + 1 * HDIM + lane] = f2bf(z1);
      A[nl][HDIM + 2 * HDIM + lane] = f2bf(z2);
      A[nl][HDIM + 3 * HDIM + lane] = f2bf(z3);
    } else {
      #pragma unroll
      for (int b = 0; b < NB; ++b) A[nl][HDIM + b * HDIM + lane] = 0;
    }
  }
  __syncthreads();

  // MFMA: [16 x 320] @ [320 x 64]
  int m16 = lane & 15, khi = lane >> 4;
  int colbase = wid * 16;
  f32x4 acc = {0.f, 0.f, 0.f, 0.f};
  #pragma unroll
  for (int kk = 0; kk < KC2; kk += 32) {
    int k0 = kk + khi * 8;
    short8 av = *(const short8*)&A[m16][k0];
    short8 bv = *(const short8*)&wt[(uint)(colbase + m16) * KC2 + k0];
    acc = __builtin_amdgcn_mfma_f32_16x16x32_bf16(
        __builtin_bit_cast(bf16x8, av), __builtin_bit_cast(bf16x8, bv), acc, 0, 0, 0);
  }
  int j = colbase + m16;
  float bj = bias[j];
  if (!last) {
    #pragma unroll
    for (int r = 0; r < 4; ++r) {
      int nl = khi * 4 + r;
      int n = nb0 + nl;
      if (n < N) {
        float hs = bf2f(A[nl][j]);                 // self row (residual base)
        float hn = hs + fmaxf(acc[r] + bj, 0.f);
        hb_out[(uint)n * HDIM + j] = f2bf(hn);
      }
    }
  } else {
    // fused lin2: out[n] = h3[n] @ W2 + b2
    float w0 = w2[j * 2], w1 = w2[j * 2 + 1];
    #pragma unroll
    for (int r = 0; r < 4; ++r) {
      int nl = khi * 4 + r;
      int n = nb0 + nl;
      float hn = 0.f;
      if (n < N) {
        float hs = bf2f(A[nl][j]);
        hn = hs + fmaxf(acc[r] + bj, 0.f);
      }
      float p0 = hn * w0, p1 = hn * w1;
      #pragma unroll
      for (int o = 1; o < 16; o <<= 1) {
        p0 += __shfl_xor(p0, o);
        p1 += __shfl_xor(p1, o);
      }
      if (m16 == 0 && n < N) {
        atomicAdd(&accO[nl][0], p0);
        atomicAdd(&accO[nl][1], p1);
      }
    }
    __syncthreads();
    if (threadIdx.x < NPB * 2) {
      int nl = threadIdx.x >> 1, o = threadIdx.x & 1;
      int n = nb0 + nl;
      if (n < N) out[2 * n + o] = accO[nl][o] + b2[o];
    }
  }
}

extern "C" void kernel_launch(void* const* d_in, const int* in_sizes, int n_in,
                              void* d_out, int out_size, void* d_ws, size_t ws_size,
                              hipStream_t stream) {
  const float* x      = (const float*)d_in[0];
  const int*   ei     = (const int*)d_in[1];
  const int*   et     = (const int*)d_in[2];
  const float* lin1_w = (const float*)d_in[3];
  const float* lin1_b = (const float*)d_in[4];
  const float* bases  = (const float*)d_in[5];
  const float* comp   = (const float*)d_in[6];
  const float* root   = (const float*)d_in[7];
  const float* cbias  = (const float*)d_in[8];
  const float* lin2_w = (const float*)d_in[9];
  const float* lin2_b = (const float*)d_in[10];
  float* out = (float*)d_out;

  int N = in_sizes[0] / HDIM;
  int E = in_sizes[2];
  uint M32 = (uint)N * NSEG;
  int NBK = (int)((M32 + 1023u) >> 10);   // <= 4096 for N <= 131072
  const int* srcp = ei;
  const int* dstp = ei + E;

  char* p = (char*)d_ws;
  auto carve = [&](size_t bytes) { char* r = p; p += (bytes + 255) & ~(size_t)255; return r; };
  ushort* hb_a    = (ushort*)carve((size_t)N * HDIM * 2);
  ushort* hb_b    = (ushort*)carve((size_t)N * HDIM * 2);
  uint*   sorted  = (uint*)carve((size_t)(E + 160) * 4);  // +160: chunk preload overrun slack
  uint*   tmp     = (uint*)carve((size_t)E * 4);
  uint*   off8    = (uint*)carve((size_t)(M32 + 1) * 4);
  uint*   bcnt    = (uint*)carve(16384);
  uint*   boff    = (uint*)carve(16388);
  uint*   gcur    = (uint*)carve(16384);
  ushort* wt_lin1 = (ushort*)carve((size_t)HDIM * HDIM * 2);
  ushort* wt_conv = (ushort*)carve((size_t)2 * HDIM * KC2 * 2);
  carve((size_t)1 << 20);  // tail pad (masked-index gathers stay in ws)

  hipMemsetAsync(bcnt, 0, 16384, stream);

  int nwg = (N + NPB - 1) / NPB;

  k_prep_wt<<<(2 * HDIM * KC2 + 255) / 256, 256, 0, stream>>>(lin1_w, bases, root, wt_lin1, wt_conv);
  k_chist<<<128, 256, 0, stream>>>(srcp, dstp, et, E, bcnt);
  k_scanB<<<1, 1024, 0, stream>>>(bcnt, boff, gcur, off8, NBK, M32, (uint)E);
  k_cscat<<<128, 256, 0, stream>>>(srcp, dstp, et, E, gcur, tmp);
  k_fsort<<<NBK, 256, 0, stream>>>(boff, tmp, sorted, off8, M32);

  k_lin1<<<nwg, 256, 0, stream>>>(x, wt_lin1, lin1_b, hb_a, N);
  k_conv<<<nwg, 256, 0, stream>>>(off8, sorted, hb_a, comp, wt_conv, cbias,
                                  hb_b, N, 0, lin2_w, lin2_b, out);
  k_conv<<<nwg, 256, 0, stream>>>(off8, sorted, hb_b, comp + RREL * NB,
                                  wt_conv + HDIM * KC2, cbias + HDIM, hb_a, N, 1,
                                  lin2_w, lin2_b, out);
}

// Round 15
// 248.922 us; speedup vs baseline: 1.1486x; 1.1486x over previous
//
#include <hip/hip_runtime.h>

// ResRGCN: h=x@W1+b1; 2x {per-(dst,rel) mean aggr -> basis-space GEMM + residual}; out=h@W2+b2
// Layer 3 of the reference is dead (output discarded) and is skipped.
// out_conv = [h | z0..z3] @ [root; B_0..B_3] + bias, z_b = sum_r comp[r,b]*mean_r.
// Edge sort: 2-level LDS-binned radix (coarse key>>10, fine 10b) -- no global
// fine-grained atomics, ~1x write amplification (r12 post-mortem fix).
// Conv engine: chunk-16 readfirstlane SGPR-base gather walk (r6/r12/r13).
// REVERT of r14's L2-tiling (node-major sweep has no cross-block phase alignment;
// 32 segs/node quadrupled walk cost: 82->106us). r13 = best measured (249us).
// Conv floor ~82us = per-CU random-gather miss-service wall, confirmed across
// 7 engine designs (r5/r6/r8/r9/r11/r13/r14); fp8 rows rejected on precision.

#define HDIM 64
#define RREL 8
#define NB   4     // bases
#define KC2  320   // 64 (self) + 4*64 (basis)
#define NPB  16    // nodes per workgroup
#define APAD 328   // padded LDS row

typedef short  short8 __attribute__((ext_vector_type(8)));
typedef __bf16 bf16x8 __attribute__((ext_vector_type(8)));
typedef float  f32x4  __attribute__((ext_vector_type(4)));
typedef unsigned int uint;
typedef unsigned short ushort;

static __device__ __forceinline__ ushort f2bf(float f) {
  uint u = __builtin_bit_cast(uint, f);
  u += 0x7FFFu + ((u >> 16) & 1u);
  return (ushort)(u >> 16);
}
static __device__ __forceinline__ float bf2f(ushort s) {
  uint u = ((uint)s) << 16;
  return __builtin_bit_cast(float, u);
}

// ---- weight prep: wt_lin1[j][k]=lin1_w[k][j]; wt_conv[l][j][k] = cat(root_l, B_0..B_3)^T
__global__ void k_prep_wt(const float* __restrict__ lin1_w, const float* __restrict__ bases,
                          const float* __restrict__ root,
                          ushort* __restrict__ wt_lin1, ushort* __restrict__ wt_conv) {
  int t = blockIdx.x * 256 + threadIdx.x;
  if (t < HDIM * HDIM) {
    int j = t >> 6, k = t & 63;
    wt_lin1[t] = f2bf(lin1_w[k * HDIM + j]);
  }
  if (t < 2 * HDIM * KC2) {
    int l = t / (HDIM * KC2);
    int rem = t - l * (HDIM * KC2);
    int j = rem / KC2;
    int k = rem - j * KC2;
    float v;
    if (k < HDIM) {
      v = root[(l * HDIM + k) * HDIM + j];
    } else {
      int b = (k - HDIM) >> 6;
      int i = (k - HDIM) & 63;
      v = bases[((l * NB + b) * HDIM + i) * HDIM + j];
    }
    wt_conv[t] = f2bf(v);
  }
}

// ---- A) coarse histogram: bucket = (dst*8+et) >> 10, LDS-staged
__global__ void k_chist(const int* __restrict__ dst, const int* __restrict__ et, int E,
                        uint* __restrict__ bcnt) {
  __shared__ uint cnt[1024];
  int t = threadIdx.x;
  for (int i = t; i < 1024; i += 256) cnt[i] = 0;
  __syncthreads();
  int per = (E + gridDim.x - 1) / gridDim.x;
  int e0 = blockIdx.x * per;
  int e1 = e0 + per; if (e1 > E) e1 = E;
  for (int e = e0 + t; e < e1; e += 256)
    atomicAdd(&cnt[((uint)dst[e] * RREL + (uint)et[e]) >> 10], 1u);
  __syncthreads();
  for (int i = t; i < 1024; i += 256)
    if (cnt[i]) atomicAdd(&bcnt[i], cnt[i]);
}

// ---- B) scan bucket counts -> offsets + cursors; write off8 seam
__global__ void k_scanB(const uint* __restrict__ bcnt, uint* __restrict__ boff,
                        uint* __restrict__ gcur, uint* __restrict__ off8,
                        int NBK, uint M8, uint E) {
  __shared__ uint s[1024];
  int t = threadIdx.x;
  uint v = (t < NBK) ? bcnt[t] : 0u;
  s[t] = v;
  __syncthreads();
  for (int o = 1; o < 1024; o <<= 1) {
    uint u = (t >= o) ? s[t - o] : 0u;
    __syncthreads();
    s[t] += u;
    __syncthreads();
  }
  uint ex = s[t] - v;
  if (t < NBK) { boff[t] = ex; gcur[t] = ex; }
  if (t == NBK - 1) boff[NBK] = s[t];
  if (t == 0) off8[M8] = E;
}

// ---- C) coarse scatter: LDS count -> one reservation per (WG,bucket) -> ~64B runs
__global__ void k_cscat(const int* __restrict__ src, const int* __restrict__ dst,
                        const int* __restrict__ et, int E, uint* __restrict__ gcur,
                        uint* __restrict__ tmp) {
  __shared__ uint cnt[1024];
  __shared__ uint base[1024];
  int t = threadIdx.x;
  int per = (E + gridDim.x - 1) / gridDim.x;
  int e0 = blockIdx.x * per;
  int e1 = e0 + per; if (e1 > E) e1 = E;
  for (int i = t; i < 1024; i += 256) cnt[i] = 0;
  __syncthreads();
  for (int e = e0 + t; e < e1; e += 256) {
    uint key = (uint)dst[e] * RREL + (uint)et[e];
    atomicAdd(&cnt[key >> 10], 1u);
  }
  __syncthreads();
  for (int i = t; i < 1024; i += 256) {
    uint c = cnt[i];
    base[i] = c ? atomicAdd(&gcur[i], c) : 0u;
  }
  __syncthreads();
  for (int i = t; i < 1024; i += 256) cnt[i] = 0;
  __syncthreads();
  for (int e = e0 + t; e < e1; e += 256) {
    uint key = (uint)dst[e] * RREL + (uint)et[e];
    uint b = key >> 10;
    uint pos = base[b] + atomicAdd(&cnt[b], 1u);
    tmp[pos] = (uint)src[e] | ((key & 1023u) << 17);   // src(17b) | finekey(10b)
  }
}

// ---- D) fine sort within bucket (1024 fine keys in LDS); writes off8 directly
__global__ void k_fsort(const uint* __restrict__ boff, const uint* __restrict__ tmp,
                        uint* __restrict__ sorted, uint* __restrict__ off8, uint M8) {
  __shared__ uint c2[1024];
  __shared__ uint ex[1024];
  __shared__ uint s[256];
  int t = threadIdx.x;
  uint b = blockIdx.x;
  uint bo = boff[b], be = boff[b + 1];
  for (int i = t; i < 1024; i += 256) c2[i] = 0;
  __syncthreads();
  for (uint i = bo + t; i < be; i += 256) atomicAdd(&c2[tmp[i] >> 17], 1u);
  __syncthreads();
  // 1024-entry exclusive scan, 4 per thread
  int k4 = t * 4;
  uint v0 = c2[k4], v1 = c2[k4 + 1], v2 = c2[k4 + 2], v3 = c2[k4 + 3];
  uint tsum = v0 + v1 + v2 + v3;
  s[t] = tsum;
  __syncthreads();
  for (int o = 1; o < 256; o <<= 1) {
    uint u = (t >= o) ? s[t - o] : 0u;
    __syncthreads();
    s[t] += u;
    __syncthreads();
  }
  uint e0x = s[t] - tsum;
  ex[k4]     = e0x;
  ex[k4 + 1] = e0x + v0;
  ex[k4 + 2] = e0x + v0 + v1;
  ex[k4 + 3] = e0x + v0 + v1 + v2;
  __syncthreads();
  uint gbase = b << 10;
  #pragma unroll
  for (int u = 0; u < 4; ++u) {
    uint g = gbase + (uint)(k4 + u);
    if (g < M8) off8[g] = bo + ex[k4 + u];
  }
  for (int i = t; i < 1024; i += 256) c2[i] = 0;   // reuse as cursors
  __syncthreads();
  for (uint i = bo + t; i < be; i += 256) {
    uint w = tmp[i];
    uint fk = w >> 17;
    uint pos = bo + ex[fk] + atomicAdd(&c2[fk], 1u);
    sorted[pos] = w & 0x1FFFFu;
  }
}

// ---- lin1: hb = bf16(x @ W1 + b1) (MFMA over K=64), float4 input loads
__global__ void k_lin1(const float* __restrict__ x, const ushort* __restrict__ wt,
                       const float* __restrict__ bias, ushort* __restrict__ hb, int N) {
  __shared__ ushort A[NPB][72];
  int nodebase = blockIdx.x * NPB;
  {
    int t = threadIdx.x;
    int nl = t >> 4, c = (t & 15) * 4;
    int n = nodebase + nl;
    ushort4 o = {0, 0, 0, 0};
    if (n < N) {
      f32x4 v = *(const f32x4*)&x[(size_t)n * HDIM + c];
      o.x = f2bf(v[0]); o.y = f2bf(v[1]); o.z = f2bf(v[2]); o.w = f2bf(v[3]);
    }
    *(ushort4*)&A[nl][c] = o;
  }
  __syncthreads();
  int lane = threadIdx.x & 63, wid = threadIdx.x >> 6;
  int m16 = lane & 15, khi = lane >> 4;
  int colbase = wid * 16;
  f32x4 acc = {0.f, 0.f, 0.f, 0.f};
  #pragma unroll
  for (int kk = 0; kk < HDIM; kk += 32) {
    int k0 = kk + khi * 8;
    short8 av = *(const short8*)&A[m16][k0];
    short8 bv = *(const short8*)&wt[(colbase + m16) * HDIM + k0];
    acc = __builtin_amdgcn_mfma_f32_16x16x32_bf16(
        __builtin_bit_cast(bf16x8, av), __builtin_bit_cast(bf16x8, bv), acc, 0, 0, 0);
  }
  int j = colbase + m16;
  float bj = bias[j];
  #pragma unroll
  for (int r = 0; r < 4; ++r) {
    int nl = khi * 4 + r;
    int n = nodebase + nl;
    if (n < N) hb[(size_t)n * HDIM + j] = f2bf(acc[r] + bj);
  }
}

// ---- fused RGCN layer: chunk-16 gather walk, z-basis accumulation in VGPRs,
//      MFMA [16x320]@[320x64]; last!=0 fuses lin2 and skips hb_out.
__global__ void __launch_bounds__(256, 6)
k_conv(const uint* __restrict__ off8, const uint* __restrict__ sorted,
       const ushort* __restrict__ hb_in, const float* __restrict__ compL,
       const ushort* __restrict__ wt, const float* __restrict__ bias,
       ushort* __restrict__ hb_out, int N, int last,
       const float* __restrict__ w2, const float* __restrict__ b2,
       float* __restrict__ out) {
  __shared__ ushort A[NPB][APAD];     // 10.5 KB
  __shared__ float  cmp[RREL * NB];
  __shared__ float  accO[NPB][2];
  int nb0 = blockIdx.x * NPB;
  int lane = threadIdx.x & 63, wid = threadIdx.x >> 6;

  if (threadIdx.x < RREL * NB) cmp[threadIdx.x] = compL[threadIdx.x];
  if (threadIdx.x < NPB * 2) accO[threadIdx.x >> 1][threadIdx.x & 1] = 0.f;
  {
    int t = threadIdx.x;
    int nl = t >> 4, c = (t & 15) * 4;
    int n = nb0 + nl;
    uint2 v = {0u, 0u};
    if (n < N) v = *(const uint2*)&hb_in[(size_t)n * HDIM + c];
    *(uint2*)&A[nl][c] = v;
  }
  __syncthreads();

  const ushort* hlane = hb_in + lane;
  for (int q = 0; q < 4; ++q) {
    int nl = wid * 4 + q;
    int n = nb0 + nl;
    if (n < N) {
      // boundaries: lanes 0..8 hold exact global offsets; others UINT_MAX
      uint bv = 0xFFFFFFFFu;
      if (lane < 9) bv = off8[(uint)n * RREL + (uint)lane];
      uint s0 = (uint)__builtin_amdgcn_readlane((int)bv, 0);
      uint s1 = (uint)__builtin_amdgcn_readlane((int)bv, 8);
      float run = 0.f, z0 = 0.f, z1 = 0.f, z2 = 0.f, z3 = 0.f;
      int rel = 0;
      uint prevb = s0;
      uint nextb = (uint)__builtin_amdgcn_readlane((int)bv, 1);
      for (uint base = s0; base < s1; base += 16u) {
        const uint* sp = sorted + base;
        uint4 w0 = *(const uint4*)(sp);
        uint4 w1 = *(const uint4*)(sp + 4);
        uint4 w2v = *(const uint4*)(sp + 8);
        uint4 w3 = *(const uint4*)(sp + 12);
        uint idx[16] = {w0.x, w0.y, w0.z, w0.w, w1.x, w1.y, w1.z, w1.w,
                        w2v.x, w2v.y, w2v.z, w2v.w, w3.x, w3.y, w3.z, w3.w};
        float g[16];
        #pragma unroll
        for (int j = 0; j < 16; ++j) {
          uint ij = (uint)__builtin_amdgcn_readfirstlane((int)idx[j]) & 0x1FFFFu;
          g[j] = bf2f(hlane[(size_t)ij << 6]);    // SGPR base + lane*2 voffset
        }
        uint m = s1 - base;                        // scalar
        #pragma unroll
        for (int j = 0; j < 16; ++j) {
          if ((uint)j < m) {                       // scalar guard
            uint pos = base + (uint)j;
            while (pos >= nextb) {                 // scalar flush walk -> z accum
              float mean = run * __builtin_amdgcn_rcpf(fmaxf((float)(nextb - prevb), 1.0f));
              f32x4 c4 = *(const f32x4*)&cmp[rel * NB];
              z0 += c4[0] * mean; z1 += c4[1] * mean;
              z2 += c4[2] * mean; z3 += c4[3] * mean;
              run = 0.f;
              ++rel;
              prevb = nextb;
              nextb = (uint)__builtin_amdgcn_readlane((int)bv, rel + 1);
            }
            run += g[j];
          }
        }
      }
      while (rel < RREL) {
        float mean = run * __builtin_amdgcn_rcpf(fmaxf((float)(nextb - prevb), 1.0f));
        f32x4 c4 = *(const f32x4*)&cmp[rel * NB];
        z0 += c4[0] * mean; z1 += c4[1] * mean;
        z2 += c4[2] * mean; z3 += c4[3] * mean;
        run = 0.f;
        ++rel;
        prevb = nextb;
        if (rel < RREL)
          nextb = (uint)__builtin_amdgcn_readlane((int)bv, rel + 1);
      }
      A[nl][HDIM + 0 * HDIM + lane] = f2bf(z0);
      A[nl][HDIM + 1 * HDIM + lane] = f2bf(z1);
      A[nl][HDIM + 2 * HDIM + lane] = f2bf(z2);
      A[nl][HDIM + 3 * HDIM + lane] = f2bf(z3);
    } else {
      #pragma unroll
      for (int b = 0; b < NB; ++b) A[nl][HDIM + b * HDIM + lane] = 0;
    }
  }
  __syncthreads();

  // MFMA: [16 x 320] @ [320 x 64]
  int m16 = lane & 15, khi = lane >> 4;
  int colbase = wid * 16;
  f32x4 acc = {0.f, 0.f, 0.f, 0.f};
  #pragma unroll
  for (int kk = 0; kk < KC2; kk += 32) {
    int k0 = kk + khi * 8;
    short8 av = *(const short8*)&A[m16][k0];
    short8 bv = *(const short8*)&wt[(uint)(colbase + m16) * KC2 + k0];
    acc = __builtin_amdgcn_mfma_f32_16x16x32_bf16(
        __builtin_bit_cast(bf16x8, av), __builtin_bit_cast(bf16x8, bv), acc, 0, 0, 0);
  }
  int j = colbase + m16;
  float bj = bias[j];
  if (!last) {
    #pragma unroll
    for (int r = 0; r < 4; ++r) {
      int nl = khi * 4 + r;
      int n = nb0 + nl;
      if (n < N) {
        float hs = bf2f(A[nl][j]);                 // self row (residual base)
        float hn = hs + fmaxf(acc[r] + bj, 0.f);
        hb_out[(uint)n * HDIM + j] = f2bf(hn);
      }
    }
  } else {
    // fused lin2: out[n] = h3[n] @ W2 + b2
    float w0 = w2[j * 2], w1 = w2[j * 2 + 1];
    #pragma unroll
    for (int r = 0; r < 4; ++r) {
      int nl = khi * 4 + r;
      int n = nb0 + nl;
      float hn = 0.f;
      if (n < N) {
        float hs = bf2f(A[nl][j]);
        hn = hs + fmaxf(acc[r] + bj, 0.f);
      }
      float p0 = hn * w0, p1 = hn * w1;
      #pragma unroll
      for (int o = 1; o < 16; o <<= 1) {
        p0 += __shfl_xor(p0, o);
        p1 += __shfl_xor(p1, o);
      }
      if (m16 == 0 && n < N) {
        atomicAdd(&accO[nl][0], p0);
        atomicAdd(&accO[nl][1], p1);
      }
    }
    __syncthreads();
    if (threadIdx.x < NPB * 2) {
      int nl = threadIdx.x >> 1, o = threadIdx.x & 1;
      int n = nb0 + nl;
      if (n < N) out[2 * n + o] = accO[nl][o] + b2[o];
    }
  }
}

extern "C" void kernel_launch(void* const* d_in, const int* in_sizes, int n_in,
                              void* d_out, int out_size, void* d_ws, size_t ws_size,
                              hipStream_t stream) {
  const float* x      = (const float*)d_in[0];
  const int*   ei     = (const int*)d_in[1];
  const int*   et     = (const int*)d_in[2];
  const float* lin1_w = (const float*)d_in[3];
  const float* lin1_b = (const float*)d_in[4];
  const float* bases  = (const float*)d_in[5];
  const float* comp   = (const float*)d_in[6];
  const float* root   = (const float*)d_in[7];
  const float* cbias  = (const float*)d_in[8];
  const float* lin2_w = (const float*)d_in[9];
  const float* lin2_b = (const float*)d_in[10];
  float* out = (float*)d_out;

  int N = in_sizes[0] / HDIM;
  int E = in_sizes[2];
  uint M8 = (uint)N * RREL;
  int NBK = (int)((M8 + 1023u) >> 10);    // <= 1024 for N <= 131072
  const int* srcp = ei;
  const int* dstp = ei + E;

  char* p = (char*)d_ws;
  auto carve = [&](size_t bytes) { char* r = p; p += (bytes + 255) & ~(size_t)255; return r; };
  ushort* hb_a    = (ushort*)carve((size_t)N * HDIM * 2);
  ushort* hb_b    = (ushort*)carve((size_t)N * HDIM * 2);
  uint*   sorted  = (uint*)carve((size_t)(E + 160) * 4);  // +160: chunk/preload overrun slack
  uint*   tmp     = (uint*)carve((size_t)E * 4);
  uint*   off8    = (uint*)carve((size_t)(M8 + 1) * 4);
  uint*   bcnt    = (uint*)carve(4096);
  uint*   boff    = (uint*)carve(4128);
  uint*   gcur    = (uint*)carve(4096);
  ushort* wt_lin1 = (ushort*)carve((size_t)HDIM * HDIM * 2);
  ushort* wt_conv = (ushort*)carve((size_t)2 * HDIM * KC2 * 2);
  carve((size_t)8 << 20);  // slack (masked-index gathers stay in ws)

  hipMemsetAsync(bcnt, 0, 4096, stream);

  int nwg = (N + NPB - 1) / NPB;

  k_prep_wt<<<(2 * HDIM * KC2 + 255) / 256, 256, 0, stream>>>(lin1_w, bases, root, wt_lin1, wt_conv);
  k_chist<<<128, 256, 0, stream>>>(dstp, et, E, bcnt);
  k_scanB<<<1, 1024, 0, stream>>>(bcnt, boff, gcur, off8, NBK, M8, (uint)E);
  k_cscat<<<128, 256, 0, stream>>>(srcp, dstp, et, E, gcur, tmp);
  k_fsort<<<NBK, 256, 0, stream>>>(boff, tmp, sorted, off8, M8);

  k_lin1<<<nwg, 256, 0, stream>>>(x, wt_lin1, lin1_b, hb_a, N);
  k_conv<<<nwg, 256, 0, stream>>>(off8, sorted, hb_a, comp, wt_conv, cbias,
                                  hb_b, N, 0, lin2_w, lin2_b, out);
  k_conv<<<nwg, 256, 0, stream>>>(off8, sorted, hb_b, comp + RREL * NB,
                                  wt_conv + HDIM * KC2, cbias + HDIM, hb_a, N, 1,
                                  lin2_w, lin2_b, out);
}